// Round 19
// baseline (636.048 us; speedup 1.0000x reference)
//
#include <hip/hip_runtime.h>
#include <hip/hip_fp16.h>
#include <cstdint>
#include <cstddef>

#define B_ 4
#define C_ 128
#define H_ 128
#define W_ 128
#define P_ (H_*W_)       // 16384
#define NH_ 8
#define NL_ 3
#define NP_ 4
#define HD_ 16
#define C2_ 64
#define ST_ 136          // bf16 LDS row stride (shorts)

// ---- workspace layout (float elements) ----
#define SZ_V      ((size_t)B_*NL_*P_*C_)
#define OFF_V     ((size_t)0)
#define OFF_HID   (OFF_V + SZ_V)                  // hid2 bf16 [2B][P][64]
#define SZ_HID    ((size_t)2*B_*C2_*P_)
#define OFF_ST    (OFF_HID + SZ_HID)
#define SZ_ST     ((size_t)128)
#define OFF_BE    (OFF_ST + SZ_ST)
#define SZ_BE     ((size_t)(NL_*C_))
#define OFF_WS    (OFF_BE + SZ_BE)                // split-bf16 weight planes (shorts)

// split-weight plane offsets (shorts)
#define VP_HI    0
#define VP_LO    16384
#define W1SO_HI  32768
#define W1SO_LO  40960
#define W1AW_HI  49152
#define W1AW_LO  57344
#define W2SO_HI  65536
#define W2SO_LO  77824
#define W2AW_HI  90112
#define W2AW_LO  96256
#define OP_HI    102400
#define OP_LO    118784
#define WS_TOT   135168

typedef short bf16x8 __attribute__((ext_vector_type(8)));
typedef float f32x4  __attribute__((ext_vector_type(4)));
#define MFMA16(a,b,c) __builtin_amdgcn_mfma_f32_16x16x32_bf16(a,b,c,0,0,0)

__device__ __forceinline__ bf16x8 cvt8rn(const float* __restrict__ x) {
    bf16x8 r;
#pragma unroll
    for (int j = 0; j < 8; ++j) {
        unsigned u = __float_as_uint(x[j]);
        r[j] = (short)((u + 0x7fffu + ((u >> 16) & 1u)) >> 16);
    }
    return r;
}
__device__ __forceinline__ unsigned short f2bf_rn(float f) {
    unsigned u = __float_as_uint(f);
    return (unsigned short)((u + 0x7fffu + ((u >> 16) & 1u)) >> 16);
}
__device__ __forceinline__ unsigned pkbf2(float a, float b) {
    return (unsigned)f2bf_rn(a) | ((unsigned)f2bf_rn(b) << 16);
}
__device__ __forceinline__ float bflo(unsigned u) { return __uint_as_float(u << 16); }
__device__ __forceinline__ float bfhi(unsigned u) { return __uint_as_float(u & 0xffff0000u); }
__device__ __forceinline__ unsigned pkhalf2(float a, float b) {
    return (unsigned)__half_as_ushort(__float2half_rn(a))
         | ((unsigned)__half_as_ushort(__float2half_rn(b)) << 16);
}
__device__ __forceinline__ float hlo(unsigned u) { return __half2float(__ushort_as_half((unsigned short)u)); }
__device__ __forceinline__ float hhi(unsigned u) { return __half2float(__ushort_as_half((unsigned short)(u >> 16))); }

// ---------------------------------------------------------------------------
// merged prep (unchanged)
__global__ __launch_bounds__(256) void k_prep0(
    const float* __restrict__ vp, const float* __restrict__ s1,
    const float* __restrict__ a1, const float* __restrict__ s2,
    const float* __restrict__ a2, const float* __restrict__ op,
    const float* __restrict__ vp_b, const float* __restrict__ le,
    unsigned short* __restrict__ d, float* __restrict__ bias_eff,
    float* __restrict__ stats)
{
    const int blk = blockIdx.x;
    const int tid = threadIdx.x;
    if (blk < 264) {
        const int i = blk*256 + tid;
        const float* src; int li, hb, n;
        if (i < 16384)      { src=vp; li=i;        hb=VP_HI;   n=16384; }
        else if (i < 24576) { src=s1; li=i-16384;  hb=W1SO_HI; n=8192;  }
        else if (i < 32768) { src=a1; li=i-24576;  hb=W1AW_HI; n=8192;  }
        else if (i < 45056) { src=s2; li=i-32768;  hb=W2SO_HI; n=12288; }
        else if (i < 51200) { src=a2; li=i-45056;  hb=W2AW_HI; n=6144;  }
        else                { src=op; li=i-51200;  hb=OP_HI;   n=16384; }
        float v = src[li];
        unsigned u = __float_as_uint(v);
        d[hb + li] = (unsigned short)(u >> 16);
        float rem = v - __uint_as_float(u & 0xffff0000u);
        d[hb + n + li] = (unsigned short)(__float_as_uint(rem) >> 16);
    } else {
        if (tid < 128) {
            stats[tid] = 0.f;
            for (int l = 0; l < NL_; ++l) {
                float dd = vp_b[tid];
                for (int k = 0; k < 128; ++k)
                    dd = fmaf(vp[tid*128 + k], le[l*128 + k], dd);
                bias_eff[l*128 + tid] = dd;
            }
        }
    }
}

// async staging: NCH channel rows x 64 px fp32 via global_load_lds width=16.
// ch_base global channel of row 0; wave wv covers rows [wv*(NCH/4), +NCH/4).
template<int NCH>
__device__ __forceinline__ void stage_asyncN(
    const float* __restrict__ X, int ch_base, int px0, int tid, float* __restrict__ F)
{
    const int wv = tid >> 6, lane = tid & 63;
    const int r4  = lane >> 4;            // row within quad
    const int pxq = (lane & 15) * 4;      // 16B within row
    constexpr int ISS = NCH / 16;         // issues per wave (4 rows each)
#pragma unroll
    for (int i = 0; i < ISS; ++i) {
        const int chl = wv*(NCH/4) + i*4;             // local row (quad base)
        const float* src = X + (size_t)(ch_base + chl + r4)*P_ + px0 + pxq;
        float* dst = F + chl*64;                      // wave-uniform base
        __builtin_amdgcn_global_load_lds(
            (const __attribute__((address_space(1))) unsigned*)src,
            (__attribute__((address_space(3))) unsigned*)dst, 16, 0, 0);
    }
}

// ---------------------------------------------------------------------------
// MERGED projection kernel, both roles async-staged. LDS 33 KB -> 4 blocks/CU.
// swz<768 -> vproj (K-split 2x16KB dbuf); else conv1 (32KB tile, reused for transpose).
__global__ __launch_bounds__(256) void k_proj(
    const float* __restrict__ vals, const float* __restrict__ q,
    const unsigned short* __restrict__ wsp, const float* __restrict__ bias_eff,
    const float* __restrict__ b_so, const float* __restrict__ b_aw,
    unsigned short* __restrict__ v16, unsigned short* __restrict__ hid2,
    float* __restrict__ stats)
{
    __shared__ __align__(16) unsigned char SMEM[33792];
    const int tid = threadIdx.x;
    const int wv = tid >> 6, l = tid & 63;
    const int lr = l & 15, lg = l >> 4;
    const int lid = blockIdx.x;
    const int swz = (lid & 7) * 128 + (lid >> 3);

    if (swz < 768) {
        // ======= vproj: K-split async dbuf (2 x 64ch x 64px fp32 = 2x16KB) =======
        float* F0 = (float*)SMEM;
        float* F1 = (float*)(SMEM + 16384);
        const int bl  = swz >> 6;                // 0..11
        const int lvl = bl % NL_;
        const int pxb = (swz & 63) * 256;
        const float* __restrict__ X = vals + (size_t)bl*C_*P_;

        bf16x8 Ahi[2][4], Alo[2][4];
#pragma unroll
        for (int rt = 0; rt < 2; ++rt)
#pragma unroll
            for (int t = 0; t < 4; ++t) {
                const int off = (wv*32 + rt*16 + lr)*128 + t*32 + lg*8;
                Ahi[rt][t] = *(const bf16x8*)&wsp[VP_HI + off];
                Alo[rt][t] = *(const bf16x8*)&wsp[VP_LO + off];
            }
        const float* be = bias_eff + lvl*128;

        f32x4 acc[2][4];
        stage_asyncN<64>(X, 0, pxb, tid, F0);
        __syncthreads();

        for (int hs = 0; hs < 8; ++hs) {         // 4 subtiles x 2 K-halves
            const int it = hs >> 1, kt = hs & 1;
            float* cur = (hs & 1) ? F1 : F0;
            float* nxt = (hs & 1) ? F0 : F1;
            const int px0 = pxb + it*64;
            if (hs < 7) {
                const int nit = (hs+1) >> 1, nkt = (hs+1) & 1;
                stage_asyncN<64>(X, nkt*64, pxb + nit*64, tid, nxt);
            }

            if (kt == 0) {
#pragma unroll
                for (int rt = 0; rt < 2; ++rt)
#pragma unroll
                    for (int c = 0; c < 4; ++c)
#pragma unroll
                        for (int r = 0; r < 4; ++r) acc[rt][c][r] = 0.f;
            }

#pragma unroll
            for (int s = 0; s < 8; ++s) {
                const int c = s >> 1, t2 = s & 1;
                const int t = kt*2 + t2;
                float x8[8];
#pragma unroll
                for (int j = 0; j < 8; ++j)
                    x8[j] = cur[(t2*32 + lg*8 + j)*64 + c*16 + lr];
                bf16x8 bb = cvt8rn(x8);
#pragma unroll
                for (int rt = 0; rt < 2; ++rt) {
                    acc[rt][c] = MFMA16(Ahi[rt][t], bb, acc[rt][c]);
                    acc[rt][c] = MFMA16(Alo[rt][t], bb, acc[rt][c]);
                }
            }

            if (kt == 1) {
#pragma unroll
                for (int c = 0; c < 4; ++c) {
                    const int px = px0 + c*16 + lr;
#pragma unroll
                    for (int rt = 0; rt < 2; ++rt) {
                        const int h  = wv*2 + rt;
                        const int oc = h*16 + lg*4;
                        uint2 stv;
                        stv.x = pkbf2(acc[rt][c][0] + be[oc+0], acc[rt][c][1] + be[oc+1]);
                        stv.y = pkbf2(acc[rt][c][2] + be[oc+2], acc[rt][c][3] + be[oc+3]);
                        *(uint2*)(v16 + (((size_t)bl*NH_ + h)*P_ + px)*16 + lg*4) = stv;
                    }
                }
            }
            __syncthreads();   // drains prefetch; next half staged
        }
    } else {
        // ======= conv1: async 32KB fp32 tile, reused as bf16 transpose area =======
        float* F = (float*)SMEM;                       // [128ch][64px] fp32
        unsigned short* T = (unsigned short*)SMEM;     // reused: [64px][ST_] bf16
        const int g  = swz - 768;
        const int b  = g >> 6;
        const int pxb = (g & 63) * 256;
        const int br = wv >> 1, oc0 = (wv & 1) * 32;
        const float* __restrict__ bi = br ? b_aw : b_so;
        const float* __restrict__ X  = q + (size_t)b*C_*P_;

        bf16x8 Ahi[2][4], Alo[2][4];
        {
            const int hbh = br ? W1AW_HI : W1SO_HI;
            const int hbl = br ? W1AW_LO : W1SO_LO;
#pragma unroll
            for (int rt = 0; rt < 2; ++rt)
#pragma unroll
                for (int t = 0; t < 4; ++t) {
                    const int off = (oc0 + rt*16 + lr)*128 + t*32 + lg*8;
                    Ahi[rt][t] = *(const bf16x8*)&wsp[hbh + off];
                    Alo[rt][t] = *(const bf16x8*)&wsp[hbl + off];
                }
        }

        for (int it = 0; it < 4; ++it) {
            const int px0 = pxb + it*64;
            stage_asyncN<128>(X, 0, px0, tid, F);
            __syncthreads();               // stage complete

            f32x4 acc[2][4];
#pragma unroll
            for (int rt = 0; rt < 2; ++rt)
#pragma unroll
                for (int c = 0; c < 4; ++c)
#pragma unroll
                    for (int r = 0; r < 4; ++r) acc[rt][c][r] = 0.f;

#pragma unroll
            for (int s = 0; s < 16; ++s) {
                const int c = s >> 2, t = s & 3;
                float x8[8];
#pragma unroll
                for (int j = 0; j < 8; ++j)
                    x8[j] = F[(t*32 + lg*8 + j)*64 + c*16 + lr];
                bf16x8 bb = cvt8rn(x8);
#pragma unroll
                for (int rt = 0; rt < 2; ++rt) {
                    acc[rt][c] = MFMA16(Ahi[rt][t], bb, acc[rt][c]);
                    acc[rt][c] = MFMA16(Alo[rt][t], bb, acc[rt][c]);
                }
            }
            __syncthreads();               // all F reads done; reuse as T

            // bias + GN stats + bf16 pack into transpose tile T
#pragma unroll
            for (int rt = 0; rt < 2; ++rt) {
                float s = 0.f, ss = 0.f;
#pragma unroll
                for (int c = 0; c < 4; ++c) {
                    float v0 = acc[rt][c][0] + bi[oc0 + rt*16 + lg*4 + 0];
                    float v1 = acc[rt][c][1] + bi[oc0 + rt*16 + lg*4 + 1];
                    float v2 = acc[rt][c][2] + bi[oc0 + rt*16 + lg*4 + 2];
                    float v3 = acc[rt][c][3] + bi[oc0 + rt*16 + lg*4 + 3];
                    s  += v0+v1+v2+v3;
                    ss += v0*v0+v1*v1+v2*v2+v3*v3;
                    uint2 pk;
                    pk.x = pkbf2(v0, v1);
                    pk.y = pkbf2(v2, v3);
                    *(uint2*)&T[(c*16 + lr)*ST_ + br*64 + oc0 + rt*16 + lg*4] = pk;
                }
#pragma unroll
                for (int off = 16; off > 0; off >>= 1) {
                    s  += __shfl_xor(s,  off, 64);
                    ss += __shfl_xor(ss, off, 64);
                }
                if ((l & 31) == 0) {
                    const int gg = (oc0 + rt*16 + (l >> 4)*4) >> 3;
                    atomicAdd(&stats[((br*B_ + b)*8 + gg)*2 + 0], s);
                    atomicAdd(&stats[((br*B_ + b)*8 + gg)*2 + 1], ss);
                }
            }
            __syncthreads();               // transpose visible

            // coalesced write-out: thread -> 64 bytes of one (br,px) row
            {
                const int brw = tid >> 7, pxl = (tid & 127) >> 1, half = tid & 1;
                const uint4* srcT = (const uint4*)&T[pxl*ST_ + brw*64 + half*32];
                uint4 a0 = srcT[0], a1v = srcT[1], a2v = srcT[2], a3v = srcT[3];
                unsigned short* gp = hid2 + ((size_t)(brw*B_ + b)*P_ + px0 + pxl)*64 + half*32;
                ((uint4*)gp)[0] = a0;
                ((uint4*)gp)[1] = a1v;
                ((uint4*)gp)[2] = a2v;
                ((uint4*)gp)[3] = a3v;
            }
            __syncthreads();               // T reads done before next stage
        }
    }
}

// ---------------------------------------------------------------------------
// FUSED conv2 + sampling + final conv (R16 known-good version, unchanged).
__global__ __launch_bounds__(256) void k_conv2s(
    const unsigned short* __restrict__ hid2, const float* __restrict__ stats,
    const float* __restrict__ so_g, const float* __restrict__ so_be,
    const float* __restrict__ aw_g, const float* __restrict__ aw_be,
    const unsigned short* __restrict__ wsp,
    const float* __restrict__ so_b2, const float* __restrict__ aw_b2,
    const unsigned short* __restrict__ v16,
    const float* __restrict__ op_b, float* __restrict__ outg)
{
    __shared__ float sc[2][64], sh[2][64];
    __shared__ unsigned SAB[96*66 + 48*66];
    unsigned* SA16 = SAB;
    unsigned* SB16 = SAB + 96*66;
    unsigned short* OUTB = (unsigned short*)SAB;
    const int tid = threadIdx.x;
    const int wv = tid >> 6, l = tid & 63;
    const int lr = l & 15, lg = l >> 4;

    const int lid = blockIdx.x + 256*blockIdx.y;
    const int swz = ((lid & 7) << 7) | (lid >> 3);
    const int b    = swz >> 8;
    const int tile = swz & 255;
    const int x0 = (tile & 7) * 16;
    const int y0 = (tile >> 3) * 4;

    if (tid < 128) {
        const int br = tid >> 6, c = tid & 63, g = c >> 3;
        const float ninv = 1.f/(8.f*(float)P_);
        float s  = stats[((br*B_ + b)*8 + g)*2 + 0];
        float ss = stats[((br*B_ + b)*8 + g)*2 + 1];
        float mu  = s*ninv;
        float var = ss*ninv - mu*mu;
        float rs  = rsqrtf(var + 1e-5f);
        float ga = br ? aw_g[c]  : so_g[c];
        float be = br ? aw_be[c] : so_be[c];
        sc[br][c] = ga*rs;
        sh[br][c] = be - mu*ga*rs;
    }
    __syncthreads();

    const int pxw = (y0 + wv)*W_ + x0 + lr;

    bf16x8 Bv[2];
    {
        const unsigned short* hs = hid2 + ((size_t)(0*B_ + b)*P_ + pxw)*64;
#pragma unroll
        for (int t = 0; t < 2; ++t) {
            uint4 w = *(const uint4*)&hs[t*32 + lg*8];
            const unsigned* wp = (const unsigned*)&w;
            float x8[8];
#pragma unroll
            for (int jj = 0; jj < 4; ++jj) {
                const int k0 = t*32 + lg*8 + 2*jj;
                x8[2*jj]   = fmaxf(fmaf(bflo(wp[jj]), sc[0][k0],   sh[0][k0]),   0.f);
                x8[2*jj+1] = fmaxf(fmaf(bfhi(wp[jj]), sc[0][k0+1], sh[0][k0+1]), 0.f);
            }
            Bv[t] = cvt8rn(x8);
        }
    }
#pragma unroll
    for (int tile2 = 0; tile2 < 12; ++tile2) {
        f32x4 acc; acc[0]=0.f; acc[1]=0.f; acc[2]=0.f; acc[3]=0.f;
#pragma unroll
        for (int t = 0; t < 2; ++t) {
            const int off = (tile2*16 + lr)*64 + t*32 + lg*8;
            bf16x8 ahi = *(const bf16x8*)&wsp[W2SO_HI + off];
            bf16x8 alo = *(const bf16x8*)&wsp[W2SO_LO + off];
            acc = MFMA16(ahi, Bv[t], acc);
            acc = MFMA16(alo, Bv[t], acc);
        }
#pragma unroll
        for (int rp = 0; rp < 2; ++rp) {
            const int ch = tile2*16 + lg*4 + 2*rp;
            SA16[(tile2*8 + lg*2 + rp)*66 + wv*16 + lr] =
                pkhalf2(acc[2*rp] + so_b2[ch], acc[2*rp+1] + so_b2[ch+1]);
        }
    }

    {
        const unsigned short* hs = hid2 + ((size_t)(1*B_ + b)*P_ + pxw)*64;
#pragma unroll
        for (int t = 0; t < 2; ++t) {
            uint4 w = *(const uint4*)&hs[t*32 + lg*8];
            const unsigned* wp = (const unsigned*)&w;
            float x8[8];
#pragma unroll
            for (int jj = 0; jj < 4; ++jj) {
                const int k0 = t*32 + lg*8 + 2*jj;
                x8[2*jj]   = fmaxf(fmaf(bflo(wp[jj]), sc[1][k0],   sh[1][k0]),   0.f);
                x8[2*jj+1] = fmaxf(fmaf(bfhi(wp[jj]), sc[1][k0+1], sh[1][k0+1]), 0.f);
            }
            Bv[t] = cvt8rn(x8);
        }
    }
#pragma unroll
    for (int tile2 = 0; tile2 < 6; ++tile2) {
        f32x4 acc; acc[0]=0.f; acc[1]=0.f; acc[2]=0.f; acc[3]=0.f;
#pragma unroll
        for (int t = 0; t < 2; ++t) {
            const int off = (tile2*16 + lr)*64 + t*32 + lg*8;
            bf16x8 ahi = *(const bf16x8*)&wsp[W2AW_HI + off];
            bf16x8 alo = *(const bf16x8*)&wsp[W2AW_LO + off];
            acc = MFMA16(ahi, Bv[t], acc);
            acc = MFMA16(alo, Bv[t], acc);
        }
#pragma unroll
        for (int rp = 0; rp < 2; ++rp) {
            const int ch = tile2*16 + lg*4 + 2*rp;
            SB16[(tile2*8 + lg*2 + rp)*66 + wv*16 + lr] =
                pkhalf2(acc[2*rp] + aw_b2[ch], acc[2*rp+1] + aw_b2[ch+1]);
        }
    }
    __syncthreads();

    const int hh  = tid >> 5;
    const int pl0 = (tid & 31) * 2;

    unsigned off12[2][12];
    float    aw12[2][12];
#pragma unroll
    for (int up = 0; up < 2; ++up) {
        const int pl = pl0 + up;
        float av[12];
#pragma unroll
        for (int k = 0; k < 6; ++k) {
            const unsigned w = SB16[(hh*6 + k)*66 + pl];
            av[2*k]   = hlo(w);
            av[2*k+1] = hhi(w);
        }
        float m = av[0];
#pragma unroll
        for (int s = 1; s < 12; ++s) m = fmaxf(m, av[s]);
        float sum = 0.f;
#pragma unroll
        for (int s = 0; s < 12; ++s) { av[s] = __expf(av[s]-m); sum += av[s]; }
        const float inv = 1.f/sum;
#pragma unroll
        for (int s = 0; s < 12; ++s) aw12[up][s] = av[s]*inv;
#pragma unroll
        for (int s = 0; s < 12; ++s) off12[up][s] = SA16[(hh*12 + s)*66 + pl];
    }
    __syncthreads();   // SAB is now OUTB

#pragma unroll
    for (int up = 0; up < 2; ++up) {
        const int pl = pl0 + up;
        const int x  = x0 + (pl & 15);
        const int y  = y0 + (pl >> 4);
        const float refx = (float)x * (1.f/(float)(W_-1));
        const float refy = (float)y * (1.f/(float)(H_-1));

        float acc[16];
#pragma unroll
        for (int j = 0; j < 16; ++j) acc[j] = 0.f;

#pragma unroll
        for (int lv = 0; lv < NL_; ++lv) {
            const unsigned short* vb = v16 + (((size_t)(b*NL_ + lv)*NH_ + hh)*P_)*16;
#pragma unroll
            for (int pt = 0; pt < NP_; ++pt) {
                const int s = lv*4 + pt;
                const float ox = hlo(off12[up][s]), oy = hhi(off12[up][s]);
                float lx2 = fminf(fmaxf(refx + ox*(1.f/(float)W_), 0.f), 1.f);
                float ly2 = fminf(fmaxf(refy + oy*(1.f/(float)H_), 0.f), 1.f);
                float px = fminf(fmaxf(lx2*(float)W_ - 0.5f, 0.f), (float)(W_-1));
                float py = fminf(fmaxf(ly2*(float)H_ - 0.5f, 0.f), (float)(H_-1));
                float x0f = floorf(px), y0f = floorf(py);
                float wx = px - x0f, wy = py - y0f;
                int xi0 = (int)x0f, yi0 = (int)y0f;
                int xi1 = min(xi0+1, W_-1), yi1 = min(yi0+1, H_-1);
                const uint4* t00 = (const uint4*)(vb + (size_t)(yi0*W_ + xi0)*16);
                const uint4* t01 = (const uint4*)(vb + (size_t)(yi0*W_ + xi1)*16);
                const uint4* t10 = (const uint4*)(vb + (size_t)(yi1*W_ + xi0)*16);
                const uint4* t11 = (const uint4*)(vb + (size_t)(yi1*W_ + xi1)*16);
                uint4 q00a = t00[0], q00b = t00[1];
                uint4 q01a = t01[0], q01b = t01[1];
                uint4 q10a = t10[0], q10b = t10[1];
                uint4 q11a = t11[0], q11b = t11[1];
                const float a   = aw12[up][s];
                const float a11 = a*wx*wy;
                const float a10 = a*wy - a11;
                const float a01 = a*wx - a11;
                const float a00 = a - a01 - a10 - a11;
                const unsigned* u00 = (const unsigned*)&q00a;
                const unsigned* u01 = (const unsigned*)&q01a;
                const unsigned* u10 = (const unsigned*)&q10a;
                const unsigned* u11 = (const unsigned*)&q11a;
#pragma unroll
                for (int i = 0; i < 4; ++i) {
                    float r = acc[2*i];
                    r = fmaf(a00, bflo(u00[i]), r);
                    r = fmaf(a01, bflo(u01[i]), r);
                    r = fmaf(a10, bflo(u10[i]), r);
                    r = fmaf(a11, bflo(u11[i]), r);
                    acc[2*i] = r;
                    r = acc[2*i+1];
                    r = fmaf(a00, bfhi(u00[i]), r);
                    r = fmaf(a01, bfhi(u01[i]), r);
                    r = fmaf(a10, bfhi(u10[i]), r);
                    r = fmaf(a11, bfhi(u11[i]), r);
                    acc[2*i+1] = r;
                }
                const unsigned* v00 = (const unsigned*)&q00b;
                const unsigned* v01 = (const unsigned*)&q01b;
                const unsigned* v10 = (const unsigned*)&q10b;
                const unsigned* v11 = (const unsigned*)&q11b;
#pragma unroll
                for (int i = 0; i < 4; ++i) {
                    float r = acc[8 + 2*i];
                    r = fmaf(a00, bflo(v00[i]), r);
                    r = fmaf(a01, bflo(v01[i]), r);
                    r = fmaf(a10, bflo(v10[i]), r);
                    r = fmaf(a11, bflo(v11[i]), r);
                    acc[8 + 2*i] = r;
                    r = acc[8 + 2*i + 1];
                    r = fmaf(a00, bfhi(v00[i]), r);
                    r = fmaf(a01, bfhi(v01[i]), r);
                    r = fmaf(a10, bfhi(v10[i]), r);
                    r = fmaf(a11, bfhi(v11[i]), r);
                    acc[8 + 2*i + 1] = r;
                }
            }
        }
        unsigned w8[8];
#pragma unroll
        for (int i = 0; i < 8; ++i) w8[i] = pkbf2(acc[2*i], acc[2*i+1]);
        uint4* dst = (uint4*)&OUTB[pl*ST_ + hh*HD_];
        dst[0] = make_uint4(w8[0], w8[1], w8[2], w8[3]);
        dst[1] = make_uint4(w8[4], w8[5], w8[6], w8[7]);
    }
    __syncthreads();

    bf16x8 Ohi[2][4], Olo[2][4];
#pragma unroll
    for (int rt = 0; rt < 2; ++rt)
#pragma unroll
        for (int t = 0; t < 4; ++t) {
            const int off = (wv*32 + rt*16 + lr)*128 + t*32 + lg*8;
            Ohi[rt][t] = *(const bf16x8*)&wsp[OP_HI + off];
            Olo[rt][t] = *(const bf16x8*)&wsp[OP_LO + off];
        }

    f32x4 oacc[2][4];
#pragma unroll
    for (int rt = 0; rt < 2; ++rt)
#pragma unroll
        for (int c = 0; c < 4; ++c)
#pragma unroll
            for (int r = 0; r < 4; ++r) oacc[rt][c][r] = 0.f;

#pragma unroll
    for (int s = 0; s < 16; ++s) {
        const int c = s >> 2, t = s & 3;
        bf16x8 bb = *(const bf16x8*)&OUTB[(c*16 + lr)*ST_ + t*32 + lg*8];
#pragma unroll
        for (int rt = 0; rt < 2; ++rt) {
            oacc[rt][c] = MFMA16(Ohi[rt][t], bb, oacc[rt][c]);
            oacc[rt][c] = MFMA16(Olo[rt][t], bb, oacc[rt][c]);
        }
    }

    float* ob = outg + (size_t)b*C_*P_;
#pragma unroll
    for (int rt = 0; rt < 2; ++rt)
#pragma unroll
        for (int c = 0; c < 4; ++c) {
            const int p = (y0 + c)*W_ + x0 + lr;
#pragma unroll
            for (int r = 0; r < 4; ++r) {
                const int oc = wv*32 + rt*16 + lg*4 + r;
                ob[(size_t)oc*P_ + p] = oacc[rt][c][r] + op_b[oc];
            }
        }
}

// ---------------------------------------------------------------------------
extern "C" void kernel_launch(void* const* d_in, const int* in_sizes, int n_in,
                              void* d_out, int out_size, void* d_ws, size_t ws_size,
                              hipStream_t stream)
{
    const float* query = (const float*)d_in[0];
    // d_in[1] = keys : UNUSED by reference
    const float* values = (const float*)d_in[2];
    const float* so_w1 = (const float*)d_in[3];
    const float* so_b1 = (const float*)d_in[4];
    const float* so_g  = (const float*)d_in[5];
    const float* so_be = (const float*)d_in[6];
    const float* so_w2 = (const float*)d_in[7];
    const float* so_b2 = (const float*)d_in[8];
    const float* aw_w1 = (const float*)d_in[9];
    const float* aw_b1 = (const float*)d_in[10];
    const float* aw_g  = (const float*)d_in[11];
    const float* aw_be = (const float*)d_in[12];
    const float* aw_w2 = (const float*)d_in[13];
    const float* aw_b2 = (const float*)d_in[14];
    const float* vp_w  = (const float*)d_in[15];
    const float* vp_b  = (const float*)d_in[16];
    const float* op_w  = (const float*)d_in[17];
    const float* op_b  = (const float*)d_in[18];
    const float* le    = (const float*)d_in[19];

    float* ws      = (float*)d_ws;
    unsigned short* v16  = (unsigned short*)(ws + OFF_V);
    unsigned short* hid2 = (unsigned short*)(ws + OFF_HID);
    float* stats   = ws + OFF_ST;
    float* be      = ws + OFF_BE;
    unsigned short* wsp  = (unsigned short*)(ws + OFF_WS);
    float* out     = (float*)d_out;

    k_prep0<<<dim3(265), dim3(256), 0, stream>>>(vp_w, so_w1, aw_w1, so_w2, aw_w2, op_w,
                                                 vp_b, le, wsp, be, stats);
    k_proj<<<dim3(1024), dim3(256), 0, stream>>>(values, query, wsp, be, so_b1, aw_b1,
                                                 v16, hid2, stats);
    k_conv2s<<<dim3(256, B_), dim3(256), 0, stream>>>(hid2, stats, so_g, so_be, aw_g, aw_be,
                                                      wsp, so_b2, aw_b2, v16, op_b, out);
}

// Round 20
// 179.592 us; speedup vs baseline: 3.5416x; 3.5416x over previous
//
#include <hip/hip_runtime.h>
#include <hip/hip_fp16.h>
#include <cstdint>
#include <cstddef>

#define B_ 4
#define C_ 128
#define H_ 128
#define W_ 128
#define P_ (H_*W_)       // 16384
#define NH_ 8
#define NL_ 3
#define NP_ 4
#define HD_ 16
#define C2_ 64
#define ST_ 136          // bf16 LDS row stride (shorts)

// ---- workspace layout (float elements) ----
#define SZ_V      ((size_t)B_*NL_*P_*C_)
#define OFF_V     ((size_t)0)
#define OFF_HID   (OFF_V + SZ_V)                  // hid2 bf16 [2B][P][64]
#define SZ_HID    ((size_t)2*B_*C2_*P_)
#define OFF_ST    (OFF_HID + SZ_HID)
#define SZ_ST     ((size_t)128)
#define OFF_BE    (OFF_ST + SZ_ST)
#define SZ_BE     ((size_t)(NL_*C_))
#define OFF_WS    (OFF_BE + SZ_BE)                // split-bf16 weight planes (shorts)

// split-weight plane offsets (shorts)
#define VP_HI    0
#define VP_LO    16384
#define W1SO_HI  32768
#define W1SO_LO  40960
#define W1AW_HI  49152
#define W1AW_LO  57344
#define W2SO_HI  65536
#define W2SO_LO  77824
#define W2AW_HI  90112
#define W2AW_LO  96256
#define OP_HI    102400
#define OP_LO    118784
#define WS_TOT   135168

typedef short bf16x8 __attribute__((ext_vector_type(8)));
typedef float f32x4  __attribute__((ext_vector_type(4)));
#define MFMA16(a,b,c) __builtin_amdgcn_mfma_f32_16x16x32_bf16(a,b,c,0,0,0)

__device__ __forceinline__ bf16x8 cvt8rn(const float* __restrict__ x) {
    bf16x8 r;
#pragma unroll
    for (int j = 0; j < 8; ++j) {
        unsigned u = __float_as_uint(x[j]);
        r[j] = (short)((u + 0x7fffu + ((u >> 16) & 1u)) >> 16);
    }
    return r;
}
__device__ __forceinline__ unsigned short f2bf_rn(float f) {
    unsigned u = __float_as_uint(f);
    return (unsigned short)((u + 0x7fffu + ((u >> 16) & 1u)) >> 16);
}
__device__ __forceinline__ unsigned pkbf2(float a, float b) {
    return (unsigned)f2bf_rn(a) | ((unsigned)f2bf_rn(b) << 16);
}
__device__ __forceinline__ float bflo(unsigned u) { return __uint_as_float(u << 16); }
__device__ __forceinline__ float bfhi(unsigned u) { return __uint_as_float(u & 0xffff0000u); }
__device__ __forceinline__ unsigned pkhalf2(float a, float b) {
    return (unsigned)__half_as_ushort(__float2half_rn(a))
         | ((unsigned)__half_as_ushort(__float2half_rn(b)) << 16);
}
__device__ __forceinline__ float hlo(unsigned u) { return __half2float(__ushort_as_half((unsigned short)u)); }
__device__ __forceinline__ float hhi(unsigned u) { return __half2float(__ushort_as_half((unsigned short)(u >> 16))); }

// ---------------------------------------------------------------------------
// merged prep (unchanged)
__global__ __launch_bounds__(256) void k_prep0(
    const float* __restrict__ vp, const float* __restrict__ s1,
    const float* __restrict__ a1, const float* __restrict__ s2,
    const float* __restrict__ a2, const float* __restrict__ op,
    const float* __restrict__ vp_b, const float* __restrict__ le,
    unsigned short* __restrict__ d, float* __restrict__ bias_eff,
    float* __restrict__ stats)
{
    const int blk = blockIdx.x;
    const int tid = threadIdx.x;
    if (blk < 264) {
        const int i = blk*256 + tid;
        const float* src; int li, hb, n;
        if (i < 16384)      { src=vp; li=i;        hb=VP_HI;   n=16384; }
        else if (i < 24576) { src=s1; li=i-16384;  hb=W1SO_HI; n=8192;  }
        else if (i < 32768) { src=a1; li=i-24576;  hb=W1AW_HI; n=8192;  }
        else if (i < 45056) { src=s2; li=i-32768;  hb=W2SO_HI; n=12288; }
        else if (i < 51200) { src=a2; li=i-45056;  hb=W2AW_HI; n=6144;  }
        else                { src=op; li=i-51200;  hb=OP_HI;   n=16384; }
        float v = src[li];
        unsigned u = __float_as_uint(v);
        d[hb + li] = (unsigned short)(u >> 16);
        float rem = v - __uint_as_float(u & 0xffff0000u);
        d[hb + n + li] = (unsigned short)(__float_as_uint(rem) >> 16);
    } else {
        if (tid < 128) {
            stats[tid] = 0.f;
            for (int l = 0; l < NL_; ++l) {
                float dd = vp_b[tid];
                for (int k = 0; k < 128; ++k)
                    dd = fmaf(vp[tid*128 + k], le[l*128 + k], dd);
                bias_eff[l*128 + tid] = dd;
            }
        }
    }
}

// async staging: NCH channel rows x 64 px fp32 via global_load_lds width=16.
template<int NCH>
__device__ __forceinline__ void stage_asyncN(
    const float* __restrict__ X, int ch_base, int px0, int tid, float* __restrict__ F)
{
    const int wv = tid >> 6, lane = tid & 63;
    const int r4  = lane >> 4;
    const int pxq = (lane & 15) * 4;
    constexpr int ISS = NCH / 16;
#pragma unroll
    for (int i = 0; i < ISS; ++i) {
        const int chl = wv*(NCH/4) + i*4;
        const float* src = X + (size_t)(ch_base + chl + r4)*P_ + px0 + pxq;
        float* dst = F + chl*64;
        __builtin_amdgcn_global_load_lds(
            (const __attribute__((address_space(1))) unsigned*)src,
            (__attribute__((address_space(3))) unsigned*)dst, 16, 0, 0);
    }
}

// ---------------------------------------------------------------------------
// MERGED projection kernel, both roles async-staged, LDS 33 KB.
// vproj: K-split dbuf with STATIC phase indices (fixes R19's rule-#20 scratch bug):
// half0 always in F0 (weights t=0,1), half1 always in F1 (weights t=2,3).
__global__ __launch_bounds__(256) void k_proj(
    const float* __restrict__ vals, const float* __restrict__ q,
    const unsigned short* __restrict__ wsp, const float* __restrict__ bias_eff,
    const float* __restrict__ b_so, const float* __restrict__ b_aw,
    unsigned short* __restrict__ v16, unsigned short* __restrict__ hid2,
    float* __restrict__ stats)
{
    __shared__ __align__(16) unsigned char SMEM[33792];
    const int tid = threadIdx.x;
    const int wv = tid >> 6, l = tid & 63;
    const int lr = l & 15, lg = l >> 4;
    const int lid = blockIdx.x;
    const int swz = (lid & 7) * 128 + (lid >> 3);

    if (swz < 768) {
        // ======= vproj: K-split async dbuf, static phases =======
        float* F0 = (float*)SMEM;            // always K-half 0 (ch 0..63)
        float* F1 = (float*)(SMEM + 16384);  // always K-half 1 (ch 64..127)
        const int bl  = swz >> 6;
        const int lvl = bl % NL_;
        const int pxb = (swz & 63) * 256;
        const float* __restrict__ X = vals + (size_t)bl*C_*P_;

        bf16x8 Ahi[2][4], Alo[2][4];
#pragma unroll
        for (int rt = 0; rt < 2; ++rt)
#pragma unroll
            for (int t = 0; t < 4; ++t) {
                const int off = (wv*32 + rt*16 + lr)*128 + t*32 + lg*8;
                Ahi[rt][t] = *(const bf16x8*)&wsp[VP_HI + off];
                Alo[rt][t] = *(const bf16x8*)&wsp[VP_LO + off];
            }
        const float* be = bias_eff + lvl*128;

        stage_asyncN<64>(X, 0, pxb, tid, F0);   // half0 of tile 0
        __syncthreads();

        for (int it = 0; it < 4; ++it) {
            const int px0 = pxb + it*64;

            // ---- phase 0: prefetch half1 -> F1; compute half0 from F0 (t=0,1) ----
            stage_asyncN<64>(X, 64, px0, tid, F1);

            f32x4 acc[2][4];
#pragma unroll
            for (int rt = 0; rt < 2; ++rt)
#pragma unroll
                for (int c = 0; c < 4; ++c)
#pragma unroll
                    for (int r = 0; r < 4; ++r) acc[rt][c][r] = 0.f;

#pragma unroll
            for (int s = 0; s < 8; ++s) {
                const int c = s >> 1, t2 = s & 1;     // t = t2 (0,1)
                float x8[8];
#pragma unroll
                for (int j = 0; j < 8; ++j)
                    x8[j] = F0[(t2*32 + lg*8 + j)*64 + c*16 + lr];
                bf16x8 bb = cvt8rn(x8);
#pragma unroll
                for (int rt = 0; rt < 2; ++rt) {
                    acc[rt][c] = MFMA16(Ahi[rt][t2], bb, acc[rt][c]);
                    acc[rt][c] = MFMA16(Alo[rt][t2], bb, acc[rt][c]);
                }
            }
            __syncthreads();   // half1 staged; all F0 reads done

            // ---- phase 1: prefetch next tile half0 -> F0; compute half1 from F1 (t=2,3) ----
            if (it < 3) stage_asyncN<64>(X, 0, px0 + 64, tid, F0);

#pragma unroll
            for (int s = 0; s < 8; ++s) {
                const int c = s >> 1, t2 = s & 1;     // t = 2 + t2 (2,3)
                float x8[8];
#pragma unroll
                for (int j = 0; j < 8; ++j)
                    x8[j] = F1[(t2*32 + lg*8 + j)*64 + c*16 + lr];
                bf16x8 bb = cvt8rn(x8);
#pragma unroll
                for (int rt = 0; rt < 2; ++rt) {
                    acc[rt][c] = MFMA16(Ahi[rt][2 + t2], bb, acc[rt][c]);
                    acc[rt][c] = MFMA16(Alo[rt][2 + t2], bb, acc[rt][c]);
                }
            }

#pragma unroll
            for (int c = 0; c < 4; ++c) {
                const int px = px0 + c*16 + lr;
#pragma unroll
                for (int rt = 0; rt < 2; ++rt) {
                    const int h  = wv*2 + rt;
                    const int oc = h*16 + lg*4;
                    uint2 stv;
                    stv.x = pkbf2(acc[rt][c][0] + be[oc+0], acc[rt][c][1] + be[oc+1]);
                    stv.y = pkbf2(acc[rt][c][2] + be[oc+2], acc[rt][c][3] + be[oc+3]);
                    *(uint2*)(v16 + (((size_t)bl*NH_ + h)*P_ + px)*16 + lg*4) = stv;
                }
            }
            __syncthreads();   // next half0 staged; all F1 reads done
        }
    } else {
        // ======= conv1: async 32KB fp32 tile, reused as bf16 transpose area =======
        float* F = (float*)SMEM;
        unsigned short* T = (unsigned short*)SMEM;
        const int g  = swz - 768;
        const int b  = g >> 6;
        const int pxb = (g & 63) * 256;
        const int br = wv >> 1, oc0 = (wv & 1) * 32;
        const float* __restrict__ bi = br ? b_aw : b_so;
        const float* __restrict__ X  = q + (size_t)b*C_*P_;

        bf16x8 Ahi[2][4], Alo[2][4];
        {
            const int hbh = br ? W1AW_HI : W1SO_HI;
            const int hbl = br ? W1AW_LO : W1SO_LO;
#pragma unroll
            for (int rt = 0; rt < 2; ++rt)
#pragma unroll
                for (int t = 0; t < 4; ++t) {
                    const int off = (oc0 + rt*16 + lr)*128 + t*32 + lg*8;
                    Ahi[rt][t] = *(const bf16x8*)&wsp[hbh + off];
                    Alo[rt][t] = *(const bf16x8*)&wsp[hbl + off];
                }
        }

        for (int it = 0; it < 4; ++it) {
            const int px0 = pxb + it*64;
            stage_asyncN<128>(X, 0, px0, tid, F);
            __syncthreads();

            f32x4 acc[2][4];
#pragma unroll
            for (int rt = 0; rt < 2; ++rt)
#pragma unroll
                for (int c = 0; c < 4; ++c)
#pragma unroll
                    for (int r = 0; r < 4; ++r) acc[rt][c][r] = 0.f;

#pragma unroll
            for (int s = 0; s < 16; ++s) {
                const int c = s >> 2, t = s & 3;
                float x8[8];
#pragma unroll
                for (int j = 0; j < 8; ++j)
                    x8[j] = F[(t*32 + lg*8 + j)*64 + c*16 + lr];
                bf16x8 bb = cvt8rn(x8);
#pragma unroll
                for (int rt = 0; rt < 2; ++rt) {
                    acc[rt][c] = MFMA16(Ahi[rt][t], bb, acc[rt][c]);
                    acc[rt][c] = MFMA16(Alo[rt][t], bb, acc[rt][c]);
                }
            }
            __syncthreads();   // F reads done; reuse as T

#pragma unroll
            for (int rt = 0; rt < 2; ++rt) {
                float s = 0.f, ss = 0.f;
#pragma unroll
                for (int c = 0; c < 4; ++c) {
                    float v0 = acc[rt][c][0] + bi[oc0 + rt*16 + lg*4 + 0];
                    float v1 = acc[rt][c][1] + bi[oc0 + rt*16 + lg*4 + 1];
                    float v2 = acc[rt][c][2] + bi[oc0 + rt*16 + lg*4 + 2];
                    float v3 = acc[rt][c][3] + bi[oc0 + rt*16 + lg*4 + 3];
                    s  += v0+v1+v2+v3;
                    ss += v0*v0+v1*v1+v2*v2+v3*v3;
                    uint2 pk;
                    pk.x = pkbf2(v0, v1);
                    pk.y = pkbf2(v2, v3);
                    *(uint2*)&T[(c*16 + lr)*ST_ + br*64 + oc0 + rt*16 + lg*4] = pk;
                }
#pragma unroll
                for (int off = 16; off > 0; off >>= 1) {
                    s  += __shfl_xor(s,  off, 64);
                    ss += __shfl_xor(ss, off, 64);
                }
                if ((l & 31) == 0) {
                    const int gg = (oc0 + rt*16 + (l >> 4)*4) >> 3;
                    atomicAdd(&stats[((br*B_ + b)*8 + gg)*2 + 0], s);
                    atomicAdd(&stats[((br*B_ + b)*8 + gg)*2 + 1], ss);
                }
            }
            __syncthreads();

            {
                const int brw = tid >> 7, pxl = (tid & 127) >> 1, half = tid & 1;
                const uint4* srcT = (const uint4*)&T[pxl*ST_ + brw*64 + half*32];
                uint4 a0 = srcT[0], a1v = srcT[1], a2v = srcT[2], a3v = srcT[3];
                unsigned short* gp = hid2 + ((size_t)(brw*B_ + b)*P_ + px0 + pxl)*64 + half*32;
                ((uint4*)gp)[0] = a0;
                ((uint4*)gp)[1] = a1v;
                ((uint4*)gp)[2] = a2v;
                ((uint4*)gp)[3] = a3v;
            }
            __syncthreads();
        }
    }
}

// ---------------------------------------------------------------------------
// FUSED conv2 + sampling + final conv (R16 known-good version, unchanged).
__global__ __launch_bounds__(256) void k_conv2s(
    const unsigned short* __restrict__ hid2, const float* __restrict__ stats,
    const float* __restrict__ so_g, const float* __restrict__ so_be,
    const float* __restrict__ aw_g, const float* __restrict__ aw_be,
    const unsigned short* __restrict__ wsp,
    const float* __restrict__ so_b2, const float* __restrict__ aw_b2,
    const unsigned short* __restrict__ v16,
    const float* __restrict__ op_b, float* __restrict__ outg)
{
    __shared__ float sc[2][64], sh[2][64];
    __shared__ unsigned SAB[96*66 + 48*66];
    unsigned* SA16 = SAB;
    unsigned* SB16 = SAB + 96*66;
    unsigned short* OUTB = (unsigned short*)SAB;
    const int tid = threadIdx.x;
    const int wv = tid >> 6, l = tid & 63;
    const int lr = l & 15, lg = l >> 4;

    const int lid = blockIdx.x + 256*blockIdx.y;
    const int swz = ((lid & 7) << 7) | (lid >> 3);
    const int b    = swz >> 8;
    const int tile = swz & 255;
    const int x0 = (tile & 7) * 16;
    const int y0 = (tile >> 3) * 4;

    if (tid < 128) {
        const int br = tid >> 6, c = tid & 63, g = c >> 3;
        const float ninv = 1.f/(8.f*(float)P_);
        float s  = stats[((br*B_ + b)*8 + g)*2 + 0];
        float ss = stats[((br*B_ + b)*8 + g)*2 + 1];
        float mu  = s*ninv;
        float var = ss*ninv - mu*mu;
        float rs  = rsqrtf(var + 1e-5f);
        float ga = br ? aw_g[c]  : so_g[c];
        float be = br ? aw_be[c] : so_be[c];
        sc[br][c] = ga*rs;
        sh[br][c] = be - mu*ga*rs;
    }
    __syncthreads();

    const int pxw = (y0 + wv)*W_ + x0 + lr;

    bf16x8 Bv[2];
    {
        const unsigned short* hs = hid2 + ((size_t)(0*B_ + b)*P_ + pxw)*64;
#pragma unroll
        for (int t = 0; t < 2; ++t) {
            uint4 w = *(const uint4*)&hs[t*32 + lg*8];
            const unsigned* wp = (const unsigned*)&w;
            float x8[8];
#pragma unroll
            for (int jj = 0; jj < 4; ++jj) {
                const int k0 = t*32 + lg*8 + 2*jj;
                x8[2*jj]   = fmaxf(fmaf(bflo(wp[jj]), sc[0][k0],   sh[0][k0]),   0.f);
                x8[2*jj+1] = fmaxf(fmaf(bfhi(wp[jj]), sc[0][k0+1], sh[0][k0+1]), 0.f);
            }
            Bv[t] = cvt8rn(x8);
        }
    }
#pragma unroll
    for (int tile2 = 0; tile2 < 12; ++tile2) {
        f32x4 acc; acc[0]=0.f; acc[1]=0.f; acc[2]=0.f; acc[3]=0.f;
#pragma unroll
        for (int t = 0; t < 2; ++t) {
            const int off = (tile2*16 + lr)*64 + t*32 + lg*8;
            bf16x8 ahi = *(const bf16x8*)&wsp[W2SO_HI + off];
            bf16x8 alo = *(const bf16x8*)&wsp[W2SO_LO + off];
            acc = MFMA16(ahi, Bv[t], acc);
            acc = MFMA16(alo, Bv[t], acc);
        }
#pragma unroll
        for (int rp = 0; rp < 2; ++rp) {
            const int ch = tile2*16 + lg*4 + 2*rp;
            SA16[(tile2*8 + lg*2 + rp)*66 + wv*16 + lr] =
                pkhalf2(acc[2*rp] + so_b2[ch], acc[2*rp+1] + so_b2[ch+1]);
        }
    }

    {
        const unsigned short* hs = hid2 + ((size_t)(1*B_ + b)*P_ + pxw)*64;
#pragma unroll
        for (int t = 0; t < 2; ++t) {
            uint4 w = *(const uint4*)&hs[t*32 + lg*8];
            const unsigned* wp = (const unsigned*)&w;
            float x8[8];
#pragma unroll
            for (int jj = 0; jj < 4; ++jj) {
                const int k0 = t*32 + lg*8 + 2*jj;
                x8[2*jj]   = fmaxf(fmaf(bflo(wp[jj]), sc[1][k0],   sh[1][k0]),   0.f);
                x8[2*jj+1] = fmaxf(fmaf(bfhi(wp[jj]), sc[1][k0+1], sh[1][k0+1]), 0.f);
            }
            Bv[t] = cvt8rn(x8);
        }
    }
#pragma unroll
    for (int tile2 = 0; tile2 < 6; ++tile2) {
        f32x4 acc; acc[0]=0.f; acc[1]=0.f; acc[2]=0.f; acc[3]=0.f;
#pragma unroll
        for (int t = 0; t < 2; ++t) {
            const int off = (tile2*16 + lr)*64 + t*32 + lg*8;
            bf16x8 ahi = *(const bf16x8*)&wsp[W2AW_HI + off];
            bf16x8 alo = *(const bf16x8*)&wsp[W2AW_LO + off];
            acc = MFMA16(ahi, Bv[t], acc);
            acc = MFMA16(alo, Bv[t], acc);
        }
#pragma unroll
        for (int rp = 0; rp < 2; ++rp) {
            const int ch = tile2*16 + lg*4 + 2*rp;
            SB16[(tile2*8 + lg*2 + rp)*66 + wv*16 + lr] =
                pkhalf2(acc[2*rp] + aw_b2[ch], acc[2*rp+1] + aw_b2[ch+1]);
        }
    }
    __syncthreads();

    const int hh  = tid >> 5;
    const int pl0 = (tid & 31) * 2;

    unsigned off12[2][12];
    float    aw12[2][12];
#pragma unroll
    for (int up = 0; up < 2; ++up) {
        const int pl = pl0 + up;
        float av[12];
#pragma unroll
        for (int k = 0; k < 6; ++k) {
            const unsigned w = SB16[(hh*6 + k)*66 + pl];
            av[2*k]   = hlo(w);
            av[2*k+1] = hhi(w);
        }
        float m = av[0];
#pragma unroll
        for (int s = 1; s < 12; ++s) m = fmaxf(m, av[s]);
        float sum = 0.f;
#pragma unroll
        for (int s = 0; s < 12; ++s) { av[s] = __expf(av[s]-m); sum += av[s]; }
        const float inv = 1.f/sum;
#pragma unroll
        for (int s = 0; s < 12; ++s) aw12[up][s] = av[s]*inv;
#pragma unroll
        for (int s = 0; s < 12; ++s) off12[up][s] = SA16[(hh*12 + s)*66 + pl];
    }
    __syncthreads();   // SAB is now OUTB

#pragma unroll
    for (int up = 0; up < 2; ++up) {
        const int pl = pl0 + up;
        const int x  = x0 + (pl & 15);
        const int y  = y0 + (pl >> 4);
        const float refx = (float)x * (1.f/(float)(W_-1));
        const float refy = (float)y * (1.f/(float)(H_-1));

        float acc[16];
#pragma unroll
        for (int j = 0; j < 16; ++j) acc[j] = 0.f;

#pragma unroll
        for (int lv = 0; lv < NL_; ++lv) {
            const unsigned short* vb = v16 + (((size_t)(b*NL_ + lv)*NH_ + hh)*P_)*16;
#pragma unroll
            for (int pt = 0; pt < NP_; ++pt) {
                const int s = lv*4 + pt;
                const float ox = hlo(off12[up][s]), oy = hhi(off12[up][s]);
                float lx2 = fminf(fmaxf(refx + ox*(1.f/(float)W_), 0.f), 1.f);
                float ly2 = fminf(fmaxf(refy + oy*(1.f/(float)H_), 0.f), 1.f);
                float px = fminf(fmaxf(lx2*(float)W_ - 0.5f, 0.f), (float)(W_-1));
                float py = fminf(fmaxf(ly2*(float)H_ - 0.5f, 0.f), (float)(H_-1));
                float x0f = floorf(px), y0f = floorf(py);
                float wx = px - x0f, wy = py - y0f;
                int xi0 = (int)x0f, yi0 = (int)y0f;
                int xi1 = min(xi0+1, W_-1), yi1 = min(yi0+1, H_-1);
                const uint4* t00 = (const uint4*)(vb + (size_t)(yi0*W_ + xi0)*16);
                const uint4* t01 = (const uint4*)(vb + (size_t)(yi0*W_ + xi1)*16);
                const uint4* t10 = (const uint4*)(vb + (size_t)(yi1*W_ + xi0)*16);
                const uint4* t11 = (const uint4*)(vb + (size_t)(yi1*W_ + xi1)*16);
                uint4 q00a = t00[0], q00b = t00[1];
                uint4 q01a = t01[0], q01b = t01[1];
                uint4 q10a = t10[0], q10b = t10[1];
                uint4 q11a = t11[0], q11b = t11[1];
                const float a   = aw12[up][s];
                const float a11 = a*wx*wy;
                const float a10 = a*wy - a11;
                const float a01 = a*wx - a11;
                const float a00 = a - a01 - a10 - a11;
                const unsigned* u00 = (const unsigned*)&q00a;
                const unsigned* u01 = (const unsigned*)&q01a;
                const unsigned* u10 = (const unsigned*)&q10a;
                const unsigned* u11 = (const unsigned*)&q11a;
#pragma unroll
                for (int i = 0; i < 4; ++i) {
                    float r = acc[2*i];
                    r = fmaf(a00, bflo(u00[i]), r);
                    r = fmaf(a01, bflo(u01[i]), r);
                    r = fmaf(a10, bflo(u10[i]), r);
                    r = fmaf(a11, bflo(u11[i]), r);
                    acc[2*i] = r;
                    r = acc[2*i+1];
                    r = fmaf(a00, bfhi(u00[i]), r);
                    r = fmaf(a01, bfhi(u01[i]), r);
                    r = fmaf(a10, bfhi(u10[i]), r);
                    r = fmaf(a11, bfhi(u11[i]), r);
                    acc[2*i+1] = r;
                }
                const unsigned* v00 = (const unsigned*)&q00b;
                const unsigned* v01 = (const unsigned*)&q01b;
                const unsigned* v10 = (const unsigned*)&q10b;
                const unsigned* v11 = (const unsigned*)&q11b;
#pragma unroll
                for (int i = 0; i < 4; ++i) {
                    float r = acc[8 + 2*i];
                    r = fmaf(a00, bflo(v00[i]), r);
                    r = fmaf(a01, bflo(v01[i]), r);
                    r = fmaf(a10, bflo(v10[i]), r);
                    r = fmaf(a11, bflo(v11[i]), r);
                    acc[8 + 2*i] = r;
                    r = acc[8 + 2*i + 1];
                    r = fmaf(a00, bfhi(v00[i]), r);
                    r = fmaf(a01, bfhi(v01[i]), r);
                    r = fmaf(a10, bfhi(v10[i]), r);
                    r = fmaf(a11, bfhi(v11[i]), r);
                    acc[8 + 2*i + 1] = r;
                }
            }
        }
        unsigned w8[8];
#pragma unroll
        for (int i = 0; i < 8; ++i) w8[i] = pkbf2(acc[2*i], acc[2*i+1]);
        uint4* dst = (uint4*)&OUTB[pl*ST_ + hh*HD_];
        dst[0] = make_uint4(w8[0], w8[1], w8[2], w8[3]);
        dst[1] = make_uint4(w8[4], w8[5], w8[6], w8[7]);
    }
    __syncthreads();

    bf16x8 Ohi[2][4], Olo[2][4];
#pragma unroll
    for (int rt = 0; rt < 2; ++rt)
#pragma unroll
        for (int t = 0; t < 4; ++t) {
            const int off = (wv*32 + rt*16 + lr)*128 + t*32 + lg*8;
            Ohi[rt][t] = *(const bf16x8*)&wsp[OP_HI + off];
            Olo[rt][t] = *(const bf16x8*)&wsp[OP_LO + off];
        }

    f32x4 oacc[2][4];
#pragma unroll
    for (int rt = 0; rt < 2; ++rt)
#pragma unroll
        for (int c = 0; c < 4; ++c)
#pragma unroll
            for (int r = 0; r < 4; ++r) oacc[rt][c][r] = 0.f;

#pragma unroll
    for (int s = 0; s < 16; ++s) {
        const int c = s >> 2, t = s & 3;
        bf16x8 bb = *(const bf16x8*)&OUTB[(c*16 + lr)*ST_ + t*32 + lg*8];
#pragma unroll
        for (int rt = 0; rt < 2; ++rt) {
            oacc[rt][c] = MFMA16(Ohi[rt][t], bb, oacc[rt][c]);
            oacc[rt][c] = MFMA16(Olo[rt][t], bb, oacc[rt][c]);
        }
    }

    float* ob = outg + (size_t)b*C_*P_;
#pragma unroll
    for (int rt = 0; rt < 2; ++rt)
#pragma unroll
        for (int c = 0; c < 4; ++c) {
            const int p = (y0 + c)*W_ + x0 + lr;
#pragma unroll
            for (int r = 0; r < 4; ++r) {
                const int oc = wv*32 + rt*16 + lg*4 + r;
                ob[(size_t)oc*P_ + p] = oacc[rt][c][r] + op_b[oc];
            }
        }
}

// ---------------------------------------------------------------------------
extern "C" void kernel_launch(void* const* d_in, const int* in_sizes, int n_in,
                              void* d_out, int out_size, void* d_ws, size_t ws_size,
                              hipStream_t stream)
{
    const float* query = (const float*)d_in[0];
    // d_in[1] = keys : UNUSED by reference
    const float* values = (const float*)d_in[2];
    const float* so_w1 = (const float*)d_in[3];
    const float* so_b1 = (const float*)d_in[4];
    const float* so_g  = (const float*)d_in[5];
    const float* so_be = (const float*)d_in[6];
    const float* so_w2 = (const float*)d_in[7];
    const float* so_b2 = (const float*)d_in[8];
    const float* aw_w1 = (const float*)d_in[9];
    const float* aw_b1 = (const float*)d_in[10];
    const float* aw_g  = (const float*)d_in[11];
    const float* aw_be = (const float*)d_in[12];
    const float* aw_w2 = (const float*)d_in[13];
    const float* aw_b2 = (const float*)d_in[14];
    const float* vp_w  = (const float*)d_in[15];
    const float* vp_b  = (const float*)d_in[16];
    const float* op_w  = (const float*)d_in[17];
    const float* op_b  = (const float*)d_in[18];
    const float* le    = (const float*)d_in[19];

    float* ws      = (float*)d_ws;
    unsigned short* v16  = (unsigned short*)(ws + OFF_V);
    unsigned short* hid2 = (unsigned short*)(ws + OFF_HID);
    float* stats   = ws + OFF_ST;
    float* be      = ws + OFF_BE;
    unsigned short* wsp  = (unsigned short*)(ws + OFF_WS);
    float* out     = (float*)d_out;

    k_prep0<<<dim3(265), dim3(256), 0, stream>>>(vp_w, so_w1, aw_w1, so_w2, aw_w2, op_w,
                                                 vp_b, le, wsp, be, stats);
    k_proj<<<dim3(1024), dim3(256), 0, stream>>>(values, query, wsp, be, so_b1, aw_b1,
                                                 v16, hid2, stats);
    k_conv2s<<<dim3(256, B_), dim3(256), 0, stream>>>(hid2, stats, so_g, so_be, aw_g, aw_be,
                                                      wsp, so_b2, aw_b2, v16, op_b, out);
}

// Round 21
// 166.261 us; speedup vs baseline: 3.8256x; 1.0802x over previous
//
#include <hip/hip_runtime.h>
#include <hip/hip_fp16.h>
#include <cstdint>
#include <cstddef>

#define B_ 4
#define C_ 128
#define H_ 128
#define W_ 128
#define P_ (H_*W_)       // 16384
#define NH_ 8
#define NL_ 3
#define NP_ 4
#define HD_ 16
#define C2_ 64
#define ST_ 136          // bf16 LDS row stride (shorts)
#define MP_ 34           // meta LDS row stride (words) for 32-px tile

// ---- workspace layout (float elements) ----
#define SZ_V      ((size_t)B_*NL_*P_*C_)
#define OFF_V     ((size_t)0)
#define OFF_HID   (OFF_V + SZ_V)                  // hid2 bf16 [2B][P][64]
#define SZ_HID    ((size_t)2*B_*C2_*P_)
#define OFF_ST    (OFF_HID + SZ_HID)
#define SZ_ST     ((size_t)128)
#define OFF_BE    (OFF_ST + SZ_ST)
#define SZ_BE     ((size_t)(NL_*C_))
#define OFF_WS    (OFF_BE + SZ_BE)                // split-bf16 weight planes (shorts)

// split-weight plane offsets (shorts)
#define VP_HI    0
#define VP_LO    16384
#define W1SO_HI  32768
#define W1SO_LO  40960
#define W1AW_HI  49152
#define W1AW_LO  57344
#define W2SO_HI  65536
#define W2SO_LO  77824
#define W2AW_HI  90112
#define W2AW_LO  96256
#define OP_HI    102400
#define OP_LO    118784
#define WS_TOT   135168

typedef short bf16x8 __attribute__((ext_vector_type(8)));
typedef float f32x4  __attribute__((ext_vector_type(4)));
#define MFMA16(a,b,c) __builtin_amdgcn_mfma_f32_16x16x32_bf16(a,b,c,0,0,0)

__device__ __forceinline__ bf16x8 cvt8rn(const float* __restrict__ x) {
    bf16x8 r;
#pragma unroll
    for (int j = 0; j < 8; ++j) {
        unsigned u = __float_as_uint(x[j]);
        r[j] = (short)((u + 0x7fffu + ((u >> 16) & 1u)) >> 16);
    }
    return r;
}
__device__ __forceinline__ unsigned short f2bf_rn(float f) {
    unsigned u = __float_as_uint(f);
    return (unsigned short)((u + 0x7fffu + ((u >> 16) & 1u)) >> 16);
}
__device__ __forceinline__ unsigned pkbf2(float a, float b) {
    return (unsigned)f2bf_rn(a) | ((unsigned)f2bf_rn(b) << 16);
}
__device__ __forceinline__ float bflo(unsigned u) { return __uint_as_float(u << 16); }
__device__ __forceinline__ float bfhi(unsigned u) { return __uint_as_float(u & 0xffff0000u); }
__device__ __forceinline__ unsigned pkhalf2(float a, float b) {
    return (unsigned)__half_as_ushort(__float2half_rn(a))
         | ((unsigned)__half_as_ushort(__float2half_rn(b)) << 16);
}
__device__ __forceinline__ float hlo(unsigned u) { return __half2float(__ushort_as_half((unsigned short)u)); }
__device__ __forceinline__ float hhi(unsigned u) { return __half2float(__ushort_as_half((unsigned short)(u >> 16))); }

// ---------------------------------------------------------------------------
// merged prep (unchanged)
__global__ __launch_bounds__(256) void k_prep0(
    const float* __restrict__ vp, const float* __restrict__ s1,
    const float* __restrict__ a1, const float* __restrict__ s2,
    const float* __restrict__ a2, const float* __restrict__ op,
    const float* __restrict__ vp_b, const float* __restrict__ le,
    unsigned short* __restrict__ d, float* __restrict__ bias_eff,
    float* __restrict__ stats)
{
    const int blk = blockIdx.x;
    const int tid = threadIdx.x;
    if (blk < 264) {
        const int i = blk*256 + tid;
        const float* src; int li, hb, n;
        if (i < 16384)      { src=vp; li=i;        hb=VP_HI;   n=16384; }
        else if (i < 24576) { src=s1; li=i-16384;  hb=W1SO_HI; n=8192;  }
        else if (i < 32768) { src=a1; li=i-24576;  hb=W1AW_HI; n=8192;  }
        else if (i < 45056) { src=s2; li=i-32768;  hb=W2SO_HI; n=12288; }
        else if (i < 51200) { src=a2; li=i-45056;  hb=W2AW_HI; n=6144;  }
        else                { src=op; li=i-51200;  hb=OP_HI;   n=16384; }
        float v = src[li];
        unsigned u = __float_as_uint(v);
        d[hb + li] = (unsigned short)(u >> 16);
        float rem = v - __uint_as_float(u & 0xffff0000u);
        d[hb + n + li] = (unsigned short)(__float_as_uint(rem) >> 16);
    } else {
        if (tid < 128) {
            stats[tid] = 0.f;
            for (int l = 0; l < NL_; ++l) {
                float dd = vp_b[tid];
                for (int k = 0; k < 128; ++k)
                    dd = fmaf(vp[tid*128 + k], le[l*128 + k], dd);
                bias_eff[l*128 + tid] = dd;
            }
        }
    }
}

// async staging: NCH channel rows x 64 px fp32 via global_load_lds width=16.
template<int NCH>
__device__ __forceinline__ void stage_asyncN(
    const float* __restrict__ X, int ch_base, int px0, int tid, float* __restrict__ F)
{
    const int wv = tid >> 6, lane = tid & 63;
    const int r4  = lane >> 4;
    const int pxq = (lane & 15) * 4;
    constexpr int ISS = NCH / 16;
#pragma unroll
    for (int i = 0; i < ISS; ++i) {
        const int chl = wv*(NCH/4) + i*4;
        const float* src = X + (size_t)(ch_base + chl + r4)*P_ + px0 + pxq;
        float* dst = F + chl*64;
        __builtin_amdgcn_global_load_lds(
            (const __attribute__((address_space(1))) unsigned*)src,
            (__attribute__((address_space(3))) unsigned*)dst, 16, 0, 0);
    }
}

// ---------------------------------------------------------------------------
// MERGED projection kernel (unchanged from R20).
__global__ __launch_bounds__(256) void k_proj(
    const float* __restrict__ vals, const float* __restrict__ q,
    const unsigned short* __restrict__ wsp, const float* __restrict__ bias_eff,
    const float* __restrict__ b_so, const float* __restrict__ b_aw,
    unsigned short* __restrict__ v16, unsigned short* __restrict__ hid2,
    float* __restrict__ stats)
{
    __shared__ __align__(16) unsigned char SMEM[33792];
    const int tid = threadIdx.x;
    const int wv = tid >> 6, l = tid & 63;
    const int lr = l & 15, lg = l >> 4;
    const int lid = blockIdx.x;
    const int swz = (lid & 7) * 128 + (lid >> 3);

    if (swz < 768) {
        float* F0 = (float*)SMEM;            // always K-half 0 (ch 0..63)
        float* F1 = (float*)(SMEM + 16384);  // always K-half 1 (ch 64..127)
        const int bl  = swz >> 6;
        const int lvl = bl % NL_;
        const int pxb = (swz & 63) * 256;
        const float* __restrict__ X = vals + (size_t)bl*C_*P_;

        bf16x8 Ahi[2][4], Alo[2][4];
#pragma unroll
        for (int rt = 0; rt < 2; ++rt)
#pragma unroll
            for (int t = 0; t < 4; ++t) {
                const int off = (wv*32 + rt*16 + lr)*128 + t*32 + lg*8;
                Ahi[rt][t] = *(const bf16x8*)&wsp[VP_HI + off];
                Alo[rt][t] = *(const bf16x8*)&wsp[VP_LO + off];
            }
        const float* be = bias_eff + lvl*128;

        stage_asyncN<64>(X, 0, pxb, tid, F0);
        __syncthreads();

        for (int it = 0; it < 4; ++it) {
            const int px0 = pxb + it*64;

            stage_asyncN<64>(X, 64, px0, tid, F1);

            f32x4 acc[2][4];
#pragma unroll
            for (int rt = 0; rt < 2; ++rt)
#pragma unroll
                for (int c = 0; c < 4; ++c)
#pragma unroll
                    for (int r = 0; r < 4; ++r) acc[rt][c][r] = 0.f;

#pragma unroll
            for (int s = 0; s < 8; ++s) {
                const int c = s >> 1, t2 = s & 1;
                float x8[8];
#pragma unroll
                for (int j = 0; j < 8; ++j)
                    x8[j] = F0[(t2*32 + lg*8 + j)*64 + c*16 + lr];
                bf16x8 bb = cvt8rn(x8);
#pragma unroll
                for (int rt = 0; rt < 2; ++rt) {
                    acc[rt][c] = MFMA16(Ahi[rt][t2], bb, acc[rt][c]);
                    acc[rt][c] = MFMA16(Alo[rt][t2], bb, acc[rt][c]);
                }
            }
            __syncthreads();

            if (it < 3) stage_asyncN<64>(X, 0, px0 + 64, tid, F0);

#pragma unroll
            for (int s = 0; s < 8; ++s) {
                const int c = s >> 1, t2 = s & 1;
                float x8[8];
#pragma unroll
                for (int j = 0; j < 8; ++j)
                    x8[j] = F1[(t2*32 + lg*8 + j)*64 + c*16 + lr];
                bf16x8 bb = cvt8rn(x8);
#pragma unroll
                for (int rt = 0; rt < 2; ++rt) {
                    acc[rt][c] = MFMA16(Ahi[rt][2 + t2], bb, acc[rt][c]);
                    acc[rt][c] = MFMA16(Alo[rt][2 + t2], bb, acc[rt][c]);
                }
            }

#pragma unroll
            for (int c = 0; c < 4; ++c) {
                const int px = px0 + c*16 + lr;
#pragma unroll
                for (int rt = 0; rt < 2; ++rt) {
                    const int h  = wv*2 + rt;
                    const int oc = h*16 + lg*4;
                    uint2 stv;
                    stv.x = pkbf2(acc[rt][c][0] + be[oc+0], acc[rt][c][1] + be[oc+1]);
                    stv.y = pkbf2(acc[rt][c][2] + be[oc+2], acc[rt][c][3] + be[oc+3]);
                    *(uint2*)(v16 + (((size_t)bl*NH_ + h)*P_ + px)*16 + lg*4) = stv;
                }
            }
            __syncthreads();
        }
    } else {
        float* F = (float*)SMEM;
        unsigned short* T = (unsigned short*)SMEM;
        const int g  = swz - 768;
        const int b  = g >> 6;
        const int pxb = (g & 63) * 256;
        const int br = wv >> 1, oc0 = (wv & 1) * 32;
        const float* __restrict__ bi = br ? b_aw : b_so;
        const float* __restrict__ X  = q + (size_t)b*C_*P_;

        bf16x8 Ahi[2][4], Alo[2][4];
        {
            const int hbh = br ? W1AW_HI : W1SO_HI;
            const int hbl = br ? W1AW_LO : W1SO_LO;
#pragma unroll
            for (int rt = 0; rt < 2; ++rt)
#pragma unroll
                for (int t = 0; t < 4; ++t) {
                    const int off = (oc0 + rt*16 + lr)*128 + t*32 + lg*8;
                    Ahi[rt][t] = *(const bf16x8*)&wsp[hbh + off];
                    Alo[rt][t] = *(const bf16x8*)&wsp[hbl + off];
                }
        }

        for (int it = 0; it < 4; ++it) {
            const int px0 = pxb + it*64;
            stage_asyncN<128>(X, 0, px0, tid, F);
            __syncthreads();

            f32x4 acc[2][4];
#pragma unroll
            for (int rt = 0; rt < 2; ++rt)
#pragma unroll
                for (int c = 0; c < 4; ++c)
#pragma unroll
                    for (int r = 0; r < 4; ++r) acc[rt][c][r] = 0.f;

#pragma unroll
            for (int s = 0; s < 16; ++s) {
                const int c = s >> 2, t = s & 3;
                float x8[8];
#pragma unroll
                for (int j = 0; j < 8; ++j)
                    x8[j] = F[(t*32 + lg*8 + j)*64 + c*16 + lr];
                bf16x8 bb = cvt8rn(x8);
#pragma unroll
                for (int rt = 0; rt < 2; ++rt) {
                    acc[rt][c] = MFMA16(Ahi[rt][t], bb, acc[rt][c]);
                    acc[rt][c] = MFMA16(Alo[rt][t], bb, acc[rt][c]);
                }
            }
            __syncthreads();

#pragma unroll
            for (int rt = 0; rt < 2; ++rt) {
                float s = 0.f, ss = 0.f;
#pragma unroll
                for (int c = 0; c < 4; ++c) {
                    float v0 = acc[rt][c][0] + bi[oc0 + rt*16 + lg*4 + 0];
                    float v1 = acc[rt][c][1] + bi[oc0 + rt*16 + lg*4 + 1];
                    float v2 = acc[rt][c][2] + bi[oc0 + rt*16 + lg*4 + 2];
                    float v3 = acc[rt][c][3] + bi[oc0 + rt*16 + lg*4 + 3];
                    s  += v0+v1+v2+v3;
                    ss += v0*v0+v1*v1+v2*v2+v3*v3;
                    uint2 pk;
                    pk.x = pkbf2(v0, v1);
                    pk.y = pkbf2(v2, v3);
                    *(uint2*)&T[(c*16 + lr)*ST_ + br*64 + oc0 + rt*16 + lg*4] = pk;
                }
#pragma unroll
                for (int off = 16; off > 0; off >>= 1) {
                    s  += __shfl_xor(s,  off, 64);
                    ss += __shfl_xor(ss, off, 64);
                }
                if ((l & 31) == 0) {
                    const int gg = (oc0 + rt*16 + (l >> 4)*4) >> 3;
                    atomicAdd(&stats[((br*B_ + b)*8 + gg)*2 + 0], s);
                    atomicAdd(&stats[((br*B_ + b)*8 + gg)*2 + 1], ss);
                }
            }
            __syncthreads();

            {
                const int brw = tid >> 7, pxl = (tid & 127) >> 1, half = tid & 1;
                const uint4* srcT = (const uint4*)&T[pxl*ST_ + brw*64 + half*32];
                uint4 a0 = srcT[0], a1v = srcT[1], a2v = srcT[2], a3v = srcT[3];
                unsigned short* gp = hid2 + ((size_t)(brw*B_ + b)*P_ + px0 + pxl)*64 + half*32;
                ((uint4*)gp)[0] = a0;
                ((uint4*)gp)[1] = a1v;
                ((uint4*)gp)[2] = a2v;
                ((uint4*)gp)[3] = a3v;
            }
            __syncthreads();
        }
    }
}

// ---------------------------------------------------------------------------
// FUSED conv2 + sampling + final conv -- R21: 32-px tiles (16x2), ~20.6KB LDS.
// Phase1 wave roles (all static): wv<2 -> offset tiles 0..8; wv>=2 -> offset
// tiles 9..11 + attn tiles 0..5. cg = wv&1 selects the 16-px row.
__global__ __launch_bounds__(256) void k_conv2s(
    const unsigned short* __restrict__ hid2, const float* __restrict__ stats,
    const float* __restrict__ so_g, const float* __restrict__ so_be,
    const float* __restrict__ aw_g, const float* __restrict__ aw_be,
    const unsigned short* __restrict__ wsp,
    const float* __restrict__ so_b2, const float* __restrict__ aw_b2,
    const unsigned short* __restrict__ v16,
    const float* __restrict__ op_b, float* __restrict__ outg)
{
    __shared__ float sc[2][64], sh[2][64];
    __shared__ unsigned SAB[(96 + 48)*MP_];       // 19584 B; phase3: OUTB[32][ST_]
    unsigned* SA16 = SAB;
    unsigned* SB16 = SAB + 96*MP_;
    unsigned short* OUTB = (unsigned short*)SAB;
    const int tid = threadIdx.x;
    const int wv = tid >> 6, l = tid & 63;
    const int lr = l & 15, lg = l >> 4;

    const int lid = blockIdx.x;                   // 0..2047
    const int swz = (lid & 7) * 256 + (lid >> 3); // bijective XCD swizzle
    const int b    = swz >> 9;
    const int tile = swz & 511;
    const int x0 = (tile & 7) * 16;
    const int y0 = (tile >> 3) * 2;

    if (tid < 128) {
        const int br = tid >> 6, c = tid & 63, g = c >> 3;
        const float ninv = 1.f/(8.f*(float)P_);
        float s  = stats[((br*B_ + b)*8 + g)*2 + 0];
        float ss = stats[((br*B_ + b)*8 + g)*2 + 1];
        float mu  = s*ninv;
        float var = ss*ninv - mu*mu;
        float rs  = rsqrtf(var + 1e-5f);
        float ga = br ? aw_g[c]  : so_g[c];
        float be = br ? aw_be[c] : so_be[c];
        sc[br][c] = ga*rs;
        sh[br][c] = be - mu*ga*rs;
    }
    __syncthreads();

    const int cg = wv & 1;                        // pixel row within tile
    const int pxw = (y0 + cg)*W_ + x0 + lr;

    // B fragments: branch0 (all waves); branch1 (waves 2,3 only)
    bf16x8 Bv0[2], Bv1[2];
    {
        const unsigned short* hs = hid2 + ((size_t)(0*B_ + b)*P_ + pxw)*64;
#pragma unroll
        for (int t = 0; t < 2; ++t) {
            uint4 w = *(const uint4*)&hs[t*32 + lg*8];
            const unsigned* wp = (const unsigned*)&w;
            float x8[8];
#pragma unroll
            for (int jj = 0; jj < 4; ++jj) {
                const int k0 = t*32 + lg*8 + 2*jj;
                x8[2*jj]   = fmaxf(fmaf(bflo(wp[jj]), sc[0][k0],   sh[0][k0]),   0.f);
                x8[2*jj+1] = fmaxf(fmaf(bfhi(wp[jj]), sc[0][k0+1], sh[0][k0+1]), 0.f);
            }
            Bv0[t] = cvt8rn(x8);
        }
    }
    if (wv >= 2) {
        const unsigned short* hs = hid2 + ((size_t)(1*B_ + b)*P_ + pxw)*64;
#pragma unroll
        for (int t = 0; t < 2; ++t) {
            uint4 w = *(const uint4*)&hs[t*32 + lg*8];
            const unsigned* wp = (const unsigned*)&w;
            float x8[8];
#pragma unroll
            for (int jj = 0; jj < 4; ++jj) {
                const int k0 = t*32 + lg*8 + 2*jj;
                x8[2*jj]   = fmaxf(fmaf(bflo(wp[jj]), sc[1][k0],   sh[1][k0]),   0.f);
                x8[2*jj+1] = fmaxf(fmaf(bfhi(wp[jj]), sc[1][k0+1], sh[1][k0+1]), 0.f);
            }
            Bv1[t] = cvt8rn(x8);
        }
    }

    if (wv < 2) {
        // offset tiles 0..8
#pragma unroll
        for (int i = 0; i < 9; ++i) {
            f32x4 acc; acc[0]=0.f; acc[1]=0.f; acc[2]=0.f; acc[3]=0.f;
#pragma unroll
            for (int t = 0; t < 2; ++t) {
                const int off = (i*16 + lr)*64 + t*32 + lg*8;
                bf16x8 ahi = *(const bf16x8*)&wsp[W2SO_HI + off];
                bf16x8 alo = *(const bf16x8*)&wsp[W2SO_LO + off];
                acc = MFMA16(ahi, Bv0[t], acc);
                acc = MFMA16(alo, Bv0[t], acc);
            }
#pragma unroll
            for (int rp = 0; rp < 2; ++rp) {
                const int ch = i*16 + lg*4 + 2*rp;
                SA16[(i*8 + lg*2 + rp)*MP_ + cg*16 + lr] =
                    pkhalf2(acc[2*rp] + so_b2[ch], acc[2*rp+1] + so_b2[ch+1]);
            }
        }
    } else {
        // offset tiles 9..11
#pragma unroll
        for (int i = 0; i < 3; ++i) {
            const int tt = 9 + i;
            f32x4 acc; acc[0]=0.f; acc[1]=0.f; acc[2]=0.f; acc[3]=0.f;
#pragma unroll
            for (int t = 0; t < 2; ++t) {
                const int off = (tt*16 + lr)*64 + t*32 + lg*8;
                bf16x8 ahi = *(const bf16x8*)&wsp[W2SO_HI + off];
                bf16x8 alo = *(const bf16x8*)&wsp[W2SO_LO + off];
                acc = MFMA16(ahi, Bv0[t], acc);
                acc = MFMA16(alo, Bv0[t], acc);
            }
#pragma unroll
            for (int rp = 0; rp < 2; ++rp) {
                const int ch = tt*16 + lg*4 + 2*rp;
                SA16[(tt*8 + lg*2 + rp)*MP_ + cg*16 + lr] =
                    pkhalf2(acc[2*rp] + so_b2[ch], acc[2*rp+1] + so_b2[ch+1]);
            }
        }
        // attn tiles 0..5
#pragma unroll
        for (int i = 0; i < 6; ++i) {
            f32x4 acc; acc[0]=0.f; acc[1]=0.f; acc[2]=0.f; acc[3]=0.f;
#pragma unroll
            for (int t = 0; t < 2; ++t) {
                const int off = (i*16 + lr)*64 + t*32 + lg*8;
                bf16x8 ahi = *(const bf16x8*)&wsp[W2AW_HI + off];
                bf16x8 alo = *(const bf16x8*)&wsp[W2AW_LO + off];
                acc = MFMA16(ahi, Bv1[t], acc);
                acc = MFMA16(alo, Bv1[t], acc);
            }
#pragma unroll
            for (int rp = 0; rp < 2; ++rp) {
                const int ch = i*16 + lg*4 + 2*rp;
                SB16[(i*8 + lg*2 + rp)*MP_ + cg*16 + lr] =
                    pkhalf2(acc[2*rp] + aw_b2[ch], acc[2*rp+1] + aw_b2[ch+1]);
            }
        }
    }
    __syncthreads();

    // ---- phase 2: preload meta (1 unit/thread), barrier, gather ----
    const int hh = tid >> 5;             // 0..7
    const int pl = tid & 31;             // 0..31

    float aw12[12];
    unsigned off12[12];
    {
        float av[12];
#pragma unroll
        for (int k = 0; k < 6; ++k) {
            const unsigned w = SB16[(hh*6 + k)*MP_ + pl];
            av[2*k]   = hlo(w);
            av[2*k+1] = hhi(w);
        }
        float m = av[0];
#pragma unroll
        for (int s = 1; s < 12; ++s) m = fmaxf(m, av[s]);
        float sum = 0.f;
#pragma unroll
        for (int s = 0; s < 12; ++s) { av[s] = __expf(av[s]-m); sum += av[s]; }
        const float inv = 1.f/sum;
#pragma unroll
        for (int s = 0; s < 12; ++s) aw12[s] = av[s]*inv;
#pragma unroll
        for (int s = 0; s < 12; ++s) off12[s] = SA16[(hh*12 + s)*MP_ + pl];
    }
    __syncthreads();   // SAB is now OUTB

    {
        const int x = x0 + (pl & 15);
        const int y = y0 + (pl >> 4);
        const float refx = (float)x * (1.f/(float)(W_-1));
        const float refy = (float)y * (1.f/(float)(H_-1));

        float acc[16];
#pragma unroll
        for (int j = 0; j < 16; ++j) acc[j] = 0.f;

#pragma unroll
        for (int lv = 0; lv < NL_; ++lv) {
            const unsigned short* vb = v16 + (((size_t)(b*NL_ + lv)*NH_ + hh)*P_)*16;
#pragma unroll
            for (int pt = 0; pt < NP_; ++pt) {
                const int s = lv*4 + pt;
                const float ox = hlo(off12[s]), oy = hhi(off12[s]);
                float lx2 = fminf(fmaxf(refx + ox*(1.f/(float)W_), 0.f), 1.f);
                float ly2 = fminf(fmaxf(refy + oy*(1.f/(float)H_), 0.f), 1.f);
                float px = fminf(fmaxf(lx2*(float)W_ - 0.5f, 0.f), (float)(W_-1));
                float py = fminf(fmaxf(ly2*(float)H_ - 0.5f, 0.f), (float)(H_-1));
                float x0f = floorf(px), y0f = floorf(py);
                float wx = px - x0f, wy = py - y0f;
                int xi0 = (int)x0f, yi0 = (int)y0f;
                int xi1 = min(xi0+1, W_-1), yi1 = min(yi0+1, H_-1);
                const uint4* t00 = (const uint4*)(vb + (size_t)(yi0*W_ + xi0)*16);
                const uint4* t01 = (const uint4*)(vb + (size_t)(yi0*W_ + xi1)*16);
                const uint4* t10 = (const uint4*)(vb + (size_t)(yi1*W_ + xi0)*16);
                const uint4* t11 = (const uint4*)(vb + (size_t)(yi1*W_ + xi1)*16);
                uint4 q00a = t00[0], q00b = t00[1];
                uint4 q01a = t01[0], q01b = t01[1];
                uint4 q10a = t10[0], q10b = t10[1];
                uint4 q11a = t11[0], q11b = t11[1];
                const float a   = aw12[s];
                const float a11 = a*wx*wy;
                const float a10 = a*wy - a11;
                const float a01 = a*wx - a11;
                const float a00 = a - a01 - a10 - a11;
                const unsigned* u00 = (const unsigned*)&q00a;
                const unsigned* u01 = (const unsigned*)&q01a;
                const unsigned* u10 = (const unsigned*)&q10a;
                const unsigned* u11 = (const unsigned*)&q11a;
#pragma unroll
                for (int i = 0; i < 4; ++i) {
                    float r = acc[2*i];
                    r = fmaf(a00, bflo(u00[i]), r);
                    r = fmaf(a01, bflo(u01[i]), r);
                    r = fmaf(a10, bflo(u10[i]), r);
                    r = fmaf(a11, bflo(u11[i]), r);
                    acc[2*i] = r;
                    r = acc[2*i+1];
                    r = fmaf(a00, bfhi(u00[i]), r);
                    r = fmaf(a01, bfhi(u01[i]), r);
                    r = fmaf(a10, bfhi(u10[i]), r);
                    r = fmaf(a11, bfhi(u11[i]), r);
                    acc[2*i+1] = r;
                }
                const unsigned* v00 = (const unsigned*)&q00b;
                const unsigned* v01 = (const unsigned*)&q01b;
                const unsigned* v10 = (const unsigned*)&q10b;
                const unsigned* v11 = (const unsigned*)&q11b;
#pragma unroll
                for (int i = 0; i < 4; ++i) {
                    float r = acc[8 + 2*i];
                    r = fmaf(a00, bflo(v00[i]), r);
                    r = fmaf(a01, bflo(v01[i]), r);
                    r = fmaf(a10, bflo(v10[i]), r);
                    r = fmaf(a11, bflo(v11[i]), r);
                    acc[8 + 2*i] = r;
                    r = acc[8 + 2*i + 1];
                    r = fmaf(a00, bfhi(v00[i]), r);
                    r = fmaf(a01, bfhi(v01[i]), r);
                    r = fmaf(a10, bfhi(v10[i]), r);
                    r = fmaf(a11, bfhi(v11[i]), r);
                    acc[8 + 2*i + 1] = r;
                }
            }
        }
        unsigned w8[8];
#pragma unroll
        for (int i = 0; i < 8; ++i) w8[i] = pkbf2(acc[2*i], acc[2*i+1]);
        uint4* dst = (uint4*)&OUTB[pl*ST_ + hh*HD_];
        dst[0] = make_uint4(w8[0], w8[1], w8[2], w8[3]);
        dst[1] = make_uint4(w8[4], w8[5], w8[6], w8[7]);
    }
    __syncthreads();   // OUT tile complete

    // ---- phase 3: final conv from bf16 OUT tile (32 px) -> global ----
    bf16x8 Ohi[2][4], Olo[2][4];
#pragma unroll
    for (int rt = 0; rt < 2; ++rt)
#pragma unroll
        for (int t = 0; t < 4; ++t) {
            const int off = (wv*32 + rt*16 + lr)*128 + t*32 + lg*8;
            Ohi[rt][t] = *(const bf16x8*)&wsp[OP_HI + off];
            Olo[rt][t] = *(const bf16x8*)&wsp[OP_LO + off];
        }

    f32x4 oacc[2][2];
#pragma unroll
    for (int rt = 0; rt < 2; ++rt)
#pragma unroll
        for (int c = 0; c < 2; ++c)
#pragma unroll
            for (int r = 0; r < 4; ++r) oacc[rt][c][r] = 0.f;

#pragma unroll
    for (int s = 0; s < 8; ++s) {
        const int c = s >> 2, t = s & 3;
        bf16x8 bb = *(const bf16x8*)&OUTB[(c*16 + lr)*ST_ + t*32 + lg*8];
#pragma unroll
        for (int rt = 0; rt < 2; ++rt) {
            oacc[rt][c] = MFMA16(Ohi[rt][t], bb, oacc[rt][c]);
            oacc[rt][c] = MFMA16(Olo[rt][t], bb, oacc[rt][c]);
        }
    }

    float* ob = outg + (size_t)b*C_*P_;
#pragma unroll
    for (int rt = 0; rt < 2; ++rt)
#pragma unroll
        for (int c = 0; c < 2; ++c) {
            const int p = (y0 + c)*W_ + x0 + lr;
#pragma unroll
            for (int r = 0; r < 4; ++r) {
                const int oc = wv*32 + rt*16 + lg*4 + r;
                ob[(size_t)oc*P_ + p] = oacc[rt][c][r] + op_b[oc];
            }
        }
}

// ---------------------------------------------------------------------------
extern "C" void kernel_launch(void* const* d_in, const int* in_sizes, int n_in,
                              void* d_out, int out_size, void* d_ws, size_t ws_size,
                              hipStream_t stream)
{
    const float* query = (const float*)d_in[0];
    // d_in[1] = keys : UNUSED by reference
    const float* values = (const float*)d_in[2];
    const float* so_w1 = (const float*)d_in[3];
    const float* so_b1 = (const float*)d_in[4];
    const float* so_g  = (const float*)d_in[5];
    const float* so_be = (const float*)d_in[6];
    const float* so_w2 = (const float*)d_in[7];
    const float* so_b2 = (const float*)d_in[8];
    const float* aw_w1 = (const float*)d_in[9];
    const float* aw_b1 = (const float*)d_in[10];
    const float* aw_g  = (const float*)d_in[11];
    const float* aw_be = (const float*)d_in[12];
    const float* aw_w2 = (const float*)d_in[13];
    const float* aw_b2 = (const float*)d_in[14];
    const float* vp_w  = (const float*)d_in[15];
    const float* vp_b  = (const float*)d_in[16];
    const float* op_w  = (const float*)d_in[17];
    const float* op_b  = (const float*)d_in[18];
    const float* le    = (const float*)d_in[19];

    float* ws      = (float*)d_ws;
    unsigned short* v16  = (unsigned short*)(ws + OFF_V);
    unsigned short* hid2 = (unsigned short*)(ws + OFF_HID);
    float* stats   = ws + OFF_ST;
    float* be      = ws + OFF_BE;
    unsigned short* wsp  = (unsigned short*)(ws + OFF_WS);
    float* out     = (float*)d_out;

    k_prep0<<<dim3(265), dim3(256), 0, stream>>>(vp_w, so_w1, aw_w1, so_w2, aw_w2, op_w,
                                                 vp_b, le, wsp, be, stats);
    k_proj<<<dim3(1024), dim3(256), 0, stream>>>(values, query, wsp, be, so_b1, aw_b1,
                                                 v16, hid2, stats);
    k_conv2s<<<dim3(2048), dim3(256), 0, stream>>>(hid2, stats, so_g, so_be, aw_g, aw_be,
                                                   wsp, so_b2, aw_b2, v16, op_b, out);
}